// Round 1
// baseline (11761.166 us; speedup 1.0000x reference)
//
#include <hip/hip_runtime.h>

#define N_NODES 50000
#define N_EDGES 1600000
#define MD 128
#define NH 8
#define DV 16

// ---------------------------------------------------------------------------
// K0: build combined transposed weight B[k][j], j in [0,256):
//   j <  128 : W_value[j][k]   (value projection column j)
//   j >= 128 : W_self [j-128][k] (self projection column j-128)
// ---------------------------------------------------------------------------
__global__ void k0_prep(const float* __restrict__ Wv, const float* __restrict__ Ws,
                        float* __restrict__ B) {
    int idx = blockIdx.x * 256 + threadIdx.x;   // 128*256 = 32768 threads
    int k = idx >> 8;
    int j = idx & 255;
    float v = (j < 128) ? Wv[j * 128 + k] : Ws[(j - 128) * 128 + k];
    B[idx] = v;
}

// ---------------------------------------------------------------------------
// K1: fused GEMM  [64 rows x 256 cols per block]
//   value[n][0..127]  = inp[n] . W_value[j]
//   out  [n][0..127]  = inp[n] . W_self[j] + bias[j]   (initializes d_out)
// Register tile: 4 rows x 16 cols per thread, 256 threads.
// ---------------------------------------------------------------------------
__global__ __launch_bounds__(256) void k1_project(
    const float* __restrict__ inp, const float* __restrict__ B,
    const float* __restrict__ bias, float* __restrict__ value,
    float* __restrict__ outp) {
    __shared__ float sA[64][132];     // +4 pad: row stride 528B (16B aligned)
    __shared__ float sB[32][256];

    const int tid = threadIdx.x;
    const int n0  = blockIdx.x * 64;

    // stage A tile: 64 rows x 128 cols (float4 loads)
    #pragma unroll
    for (int i = 0; i < 8; ++i) {
        int f4 = i * 256 + tid;          // 0..2047 float4s
        int r  = f4 >> 5;                // 32 float4 per row
        int c4 = f4 & 31;
        float4 v = make_float4(0.f, 0.f, 0.f, 0.f);
        if (n0 + r < N_NODES) v = ((const float4*)(inp + (size_t)(n0 + r) * MD))[c4];
        sA[r][c4 * 4 + 0] = v.x; sA[r][c4 * 4 + 1] = v.y;
        sA[r][c4 * 4 + 2] = v.z; sA[r][c4 * 4 + 3] = v.w;
    }

    float acc[4][16];
    #pragma unroll
    for (int r = 0; r < 4; ++r)
        #pragma unroll
        for (int c = 0; c < 16; ++c) acc[r][c] = 0.f;

    const int r0 = (tid >> 4) * 4;       // 0,4,...,60
    const int c0 = (tid & 15) * 16;      // 0,16,...,240

    for (int kc = 0; kc < 4; ++kc) {
        // stage B chunk: 32 k x 256 j
        #pragma unroll
        for (int i = 0; i < 8; ++i) {
            int f4 = i * 256 + tid;       // 0..2047
            int kr = f4 >> 6;             // 64 float4 per row
            int c4 = f4 & 63;
            ((float4*)(&sB[kr][0]))[c4] =
                ((const float4*)(B + (size_t)(kc * 32 + kr) * 256))[c4];
        }
        __syncthreads();
        #pragma unroll 4
        for (int k = 0; k < 32; ++k) {
            float a0 = sA[r0 + 0][kc * 32 + k];
            float a1 = sA[r0 + 1][kc * 32 + k];
            float a2 = sA[r0 + 2][kc * 32 + k];
            float a3 = sA[r0 + 3][kc * 32 + k];
            float b[16];
            #pragma unroll
            for (int i = 0; i < 4; ++i) {
                float4 bv = ((const float4*)(&sB[k][c0]))[i];
                b[i * 4 + 0] = bv.x; b[i * 4 + 1] = bv.y;
                b[i * 4 + 2] = bv.z; b[i * 4 + 3] = bv.w;
            }
            #pragma unroll
            for (int c = 0; c < 16; ++c) {
                acc[0][c] = fmaf(a0, b[c], acc[0][c]);
                acc[1][c] = fmaf(a1, b[c], acc[1][c]);
                acc[2][c] = fmaf(a2, b[c], acc[2][c]);
                acc[3][c] = fmaf(a3, b[c], acc[3][c]);
            }
        }
        __syncthreads();
    }

    // epilogue
    #pragma unroll
    for (int r = 0; r < 4; ++r) {
        int n = n0 + r0 + r;
        if (n >= N_NODES) continue;
        if (c0 < 128) {
            float4* dst = (float4*)(value + (size_t)n * MD + c0);
            #pragma unroll
            for (int i = 0; i < 4; ++i) {
                dst[i] = make_float4(acc[r][i * 4 + 0], acc[r][i * 4 + 1],
                                     acc[r][i * 4 + 2], acc[r][i * 4 + 3]);
            }
        } else {
            int cc = c0 - 128;
            float4* dst = (float4*)(outp + (size_t)n * MD + cc);
            #pragma unroll
            for (int i = 0; i < 4; ++i) {
                dst[i] = make_float4(acc[r][i * 4 + 0] + bias[cc + i * 4 + 0],
                                     acc[r][i * 4 + 1] + bias[cc + i * 4 + 1],
                                     acc[r][i * 4 + 2] + bias[cc + i * 4 + 2],
                                     acc[r][i * 4 + 3] + bias[cc + i * 4 + 3]);
            }
        }
    }
}

// ---------------------------------------------------------------------------
// K2: per (node,head) score projections vs/vt = <value[n,h,:], w_src/tgt[h,:]>
// ---------------------------------------------------------------------------
__global__ void k2_vsvt(const float* __restrict__ value,
                        const float* __restrict__ wsrc, const float* __restrict__ wtgt,
                        float* __restrict__ vs, float* __restrict__ vt) {
    int idx = blockIdx.x * 256 + threadIdx.x;     // n*8+h
    if (idx >= N_NODES * NH) return;
    int h = idx & 7;
    const float4* vp  = (const float4*)(value + (size_t)(idx >> 3) * MD + h * DV);
    const float4* wsp = (const float4*)(wsrc + h * DV);
    const float4* wtp = (const float4*)(wtgt + h * DV);
    float s = 0.f, t = 0.f;
    #pragma unroll
    for (int i = 0; i < 4; ++i) {
        float4 v = vp[i], a = wsp[i], b = wtp[i];
        s += v.x * a.x + v.y * a.y + v.z * a.z + v.w * a.w;
        t += v.x * b.x + v.y * b.y + v.z * b.z + v.w * b.w;
    }
    vs[idx] = s;
    vt[idx] = t;
}

// ---------------------------------------------------------------------------
// K3: per (edge,head): e2 = exp(leaky(vs[src]+vt[tgt]))/dist ; denom[tgt,h] += e2
// (global max / first-softmax denom / EPS all cancel in the final renorm)
// ---------------------------------------------------------------------------
__global__ void k3_denom(const int* __restrict__ ei, const float* __restrict__ dist,
                         const float* __restrict__ vs, const float* __restrict__ vt,
                         float* __restrict__ denom) {
    int idx = blockIdx.x * 256 + threadIdx.x;     // e*8+h, 12.8M threads
    int e = idx >> 3, h = idx & 7;
    int src = ei[e], tgt = ei[N_EDGES + e];
    float s = vs[src * NH + h] + vt[tgt * NH + h];
    s = (s >= 0.f) ? s : 0.2f * s;
    float e2 = __expf(s) / dist[e];
    unsafeAtomicAdd(&denom[tgt * NH + h], e2);
}

// ---------------------------------------------------------------------------
// K4: per (edge,head): attn = e2/denom[tgt,h]; write attn; out[tgt] += attn*value[src]
// ---------------------------------------------------------------------------
__global__ void k4_agg(const int* __restrict__ ei, const float* __restrict__ dist,
                       const float* __restrict__ vs, const float* __restrict__ vt,
                       const float* __restrict__ denom, const float* __restrict__ value,
                       float* __restrict__ outp, float* __restrict__ attn_out) {
    int idx = blockIdx.x * 256 + threadIdx.x;     // e*8+h
    int e = idx >> 3, h = idx & 7;
    int src = ei[e], tgt = ei[N_EDGES + e];
    float s = vs[src * NH + h] + vt[tgt * NH + h];
    s = (s >= 0.f) ? s : 0.2f * s;
    float e2 = __expf(s) / dist[e];
    float attn = e2 / denom[tgt * NH + h];
    attn_out[(size_t)e * NH + h] = attn;
    const float4* vrow = (const float4*)(value + (size_t)src * MD + h * DV);
    float* orow = outp + (size_t)tgt * MD + h * DV;
    #pragma unroll
    for (int i = 0; i < 4; ++i) {
        float4 v = vrow[i];
        unsafeAtomicAdd(orow + i * 4 + 0, attn * v.x);
        unsafeAtomicAdd(orow + i * 4 + 1, attn * v.y);
        unsafeAtomicAdd(orow + i * 4 + 2, attn * v.z);
        unsafeAtomicAdd(orow + i * 4 + 3, attn * v.w);
    }
}

// ---------------------------------------------------------------------------
extern "C" void kernel_launch(void* const* d_in, const int* in_sizes, int n_in,
                              void* d_out, int out_size, void* d_ws, size_t ws_size,
                              hipStream_t stream) {
    const float* inp  = (const float*)d_in[0];
    const int*   ei   = (const int*)d_in[1];
    const float* dist = (const float*)d_in[2];
    // d_in[3] = deparc_edge: unused by the reference
    const float* Wv   = (const float*)d_in[4];
    const float* wsrc = (const float*)d_in[5];
    const float* wtgt = (const float*)d_in[6];
    const float* Ws   = (const float*)d_in[7];
    const float* bias = (const float*)d_in[8];

    float* outp = (float*)d_out;                       // [N,128]
    float* attn = outp + (size_t)N_NODES * MD;         // [E,8]

    float* ws    = (float*)d_ws;
    float* B     = ws;                                  // 32768
    float* value = B + 32768;                           // N*128 = 6.4M
    float* vs    = value + (size_t)N_NODES * MD;        // N*8
    float* vt    = vs + N_NODES * NH;                   // N*8
    float* denom = vt + N_NODES * NH;                   // N*8

    hipMemsetAsync(denom, 0, (size_t)N_NODES * NH * sizeof(float), stream);

    k0_prep<<<128, 256, 0, stream>>>(Wv, Ws, B);
    k1_project<<<(N_NODES + 63) / 64, 256, 0, stream>>>(inp, B, bias, value, outp);
    k2_vsvt<<<(N_NODES * NH + 255) / 256, 256, 0, stream>>>(value, wsrc, wtgt, vs, vt);
    k3_denom<<<(N_EDGES * NH) / 256, 256, 0, stream>>>(ei, dist, vs, vt, denom);
    k4_agg<<<(N_EDGES * NH) / 256, 256, 0, stream>>>(ei, dist, vs, vt, denom, value, outp, attn);
}

// Round 2
// 598.270 us; speedup vs baseline: 19.6586x; 19.6586x over previous
//
#include <hip/hip_runtime.h>

#define N_NODES 50000
#define N_EDGES 1600000
#define MD 128
#define NH 8
#define DV 16
#define SCAN_NBLK 196   // 196*256 = 50176 >= N_NODES

// ---------------------------------------------------------------------------
// K0: build combined transposed weight B[k][j], j in [0,256):
//   j < 128 : W_value[j][k] ;  j >= 128 : W_self[j-128][k]
// ---------------------------------------------------------------------------
__global__ void k0_prep(const float* __restrict__ Wv, const float* __restrict__ Ws,
                        float* __restrict__ B) {
    int idx = blockIdx.x * 256 + threadIdx.x;
    int k = idx >> 8;
    int j = idx & 255;
    B[idx] = (j < 128) ? Wv[j * 128 + k] : Ws[(j - 128) * 128 + k];
}

// ---------------------------------------------------------------------------
// K1: fused GEMM: value = inp@Wv^T ; outp = inp@Ws^T + bias
// ---------------------------------------------------------------------------
__global__ __launch_bounds__(256) void k1_project(
    const float* __restrict__ inp, const float* __restrict__ B,
    const float* __restrict__ bias, float* __restrict__ value,
    float* __restrict__ outp) {
    __shared__ float sA[64][132];
    __shared__ float sB[32][256];

    const int tid = threadIdx.x;
    const int n0  = blockIdx.x * 64;

    #pragma unroll
    for (int i = 0; i < 8; ++i) {
        int f4 = i * 256 + tid;
        int r  = f4 >> 5;
        int c4 = f4 & 31;
        float4 v = make_float4(0.f, 0.f, 0.f, 0.f);
        if (n0 + r < N_NODES) v = ((const float4*)(inp + (size_t)(n0 + r) * MD))[c4];
        sA[r][c4 * 4 + 0] = v.x; sA[r][c4 * 4 + 1] = v.y;
        sA[r][c4 * 4 + 2] = v.z; sA[r][c4 * 4 + 3] = v.w;
    }

    float acc[4][16];
    #pragma unroll
    for (int r = 0; r < 4; ++r)
        #pragma unroll
        for (int c = 0; c < 16; ++c) acc[r][c] = 0.f;

    const int r0 = (tid >> 4) * 4;
    const int c0 = (tid & 15) * 16;

    for (int kc = 0; kc < 4; ++kc) {
        #pragma unroll
        for (int i = 0; i < 8; ++i) {
            int f4 = i * 256 + tid;
            int kr = f4 >> 6;
            int c4 = f4 & 63;
            ((float4*)(&sB[kr][0]))[c4] =
                ((const float4*)(B + (size_t)(kc * 32 + kr) * 256))[c4];
        }
        __syncthreads();
        #pragma unroll 4
        for (int k = 0; k < 32; ++k) {
            float a0 = sA[r0 + 0][kc * 32 + k];
            float a1 = sA[r0 + 1][kc * 32 + k];
            float a2 = sA[r0 + 2][kc * 32 + k];
            float a3 = sA[r0 + 3][kc * 32 + k];
            float b[16];
            #pragma unroll
            for (int i = 0; i < 4; ++i) {
                float4 bv = ((const float4*)(&sB[k][c0]))[i];
                b[i * 4 + 0] = bv.x; b[i * 4 + 1] = bv.y;
                b[i * 4 + 2] = bv.z; b[i * 4 + 3] = bv.w;
            }
            #pragma unroll
            for (int c = 0; c < 16; ++c) {
                acc[0][c] = fmaf(a0, b[c], acc[0][c]);
                acc[1][c] = fmaf(a1, b[c], acc[1][c]);
                acc[2][c] = fmaf(a2, b[c], acc[2][c]);
                acc[3][c] = fmaf(a3, b[c], acc[3][c]);
            }
        }
        __syncthreads();
    }

    #pragma unroll
    for (int r = 0; r < 4; ++r) {
        int n = n0 + r0 + r;
        if (n >= N_NODES) continue;
        if (c0 < 128) {
            float4* dst = (float4*)(value + (size_t)n * MD + c0);
            #pragma unroll
            for (int i = 0; i < 4; ++i)
                dst[i] = make_float4(acc[r][i * 4 + 0], acc[r][i * 4 + 1],
                                     acc[r][i * 4 + 2], acc[r][i * 4 + 3]);
        } else {
            int cc = c0 - 128;
            float4* dst = (float4*)(outp + (size_t)n * MD + cc);
            #pragma unroll
            for (int i = 0; i < 4; ++i)
                dst[i] = make_float4(acc[r][i * 4 + 0] + bias[cc + i * 4 + 0],
                                     acc[r][i * 4 + 1] + bias[cc + i * 4 + 1],
                                     acc[r][i * 4 + 2] + bias[cc + i * 4 + 2],
                                     acc[r][i * 4 + 3] + bias[cc + i * 4 + 3]);
        }
    }
}

// ---------------------------------------------------------------------------
// K2: vs/vt projections per (node, head)
// ---------------------------------------------------------------------------
__global__ void k2_vsvt(const float* __restrict__ value,
                        const float* __restrict__ wsrc, const float* __restrict__ wtgt,
                        float* __restrict__ vs, float* __restrict__ vt) {
    int idx = blockIdx.x * 256 + threadIdx.x;
    if (idx >= N_NODES * NH) return;
    int h = idx & 7;
    const float4* vp  = (const float4*)(value + (size_t)(idx >> 3) * MD + h * DV);
    const float4* wsp = (const float4*)(wsrc + h * DV);
    const float4* wtp = (const float4*)(wtgt + h * DV);
    float s = 0.f, t = 0.f;
    #pragma unroll
    for (int i = 0; i < 4; ++i) {
        float4 v = vp[i], a = wsp[i], b = wtp[i];
        s += v.x * a.x + v.y * a.y + v.z * a.z + v.w * a.w;
        t += v.x * b.x + v.y * b.y + v.z * b.z + v.w * b.w;
    }
    vs[idx] = s;
    vt[idx] = t;
}

// ---------------------------------------------------------------------------
// CSR build: histogram -> hierarchical scan -> fill
// ---------------------------------------------------------------------------
__global__ void k_hist(const int* __restrict__ ei, int* __restrict__ deg) {
    int e = blockIdx.x * 256 + threadIdx.x;
    if (e < N_EDGES) atomicAdd(&deg[ei[N_EDGES + e]], 1);
}

__global__ void k_scan1(const int* __restrict__ deg, int* __restrict__ rowptr,
                        int* __restrict__ bsum) {
    __shared__ int s[256];
    int t = threadIdx.x, i = blockIdx.x * 256 + t;
    int v = (i < N_NODES) ? deg[i] : 0;
    s[t] = v;
    __syncthreads();
    #pragma unroll
    for (int off = 1; off < 256; off <<= 1) {
        int x = (t >= off) ? s[t - off] : 0;
        __syncthreads();
        s[t] += x;
        __syncthreads();
    }
    if (i < N_NODES) rowptr[i] = s[t] - v;        // exclusive within block
    if (t == 255) bsum[blockIdx.x] = s[255];
}

__global__ void k_scan2(int* __restrict__ bsum, int* __restrict__ boff) {
    __shared__ int s[256];
    int t = threadIdx.x;
    int v = (t < SCAN_NBLK) ? bsum[t] : 0;
    s[t] = v;
    __syncthreads();
    #pragma unroll
    for (int off = 1; off < 256; off <<= 1) {
        int x = (t >= off) ? s[t - off] : 0;
        __syncthreads();
        s[t] += x;
        __syncthreads();
    }
    if (t < SCAN_NBLK) boff[t] = s[t] - v;        // exclusive block offsets
}

__global__ void k_scan3(int* __restrict__ rowptr, const int* __restrict__ boff,
                        int* __restrict__ cursor) {
    int i = blockIdx.x * 256 + threadIdx.x;
    if (i < N_NODES) {
        int r = rowptr[i] + boff[blockIdx.x];
        rowptr[i] = r;
        cursor[i] = r;
    }
    if (i == 0) rowptr[N_NODES] = N_EDGES;
}

__global__ void k_fill(const int* __restrict__ ei, int* __restrict__ cursor,
                       int2* __restrict__ csr) {
    int e = blockIdx.x * 256 + threadIdx.x;
    if (e >= N_EDGES) return;
    int tgt = ei[N_EDGES + e];
    int pos = atomicAdd(&cursor[tgt], 1);
    csr[pos] = make_int2(ei[e], e);               // (src, edge_id)
}

// ---------------------------------------------------------------------------
// K_GATHER: one wave per target node. Lane l: es = l>>3 (edge slot), h = l&7.
// Phase A: denom per head (butterfly over es). Phase B: attn write +
// 16-channel register accumulation of attn*value[src], reduce, single RMW.
// ---------------------------------------------------------------------------
__global__ __launch_bounds__(256) void k_gather(
    const int2* __restrict__ csr, const int* __restrict__ rowptr,
    const float* __restrict__ dist, const float* __restrict__ vs,
    const float* __restrict__ vt, const float* __restrict__ value,
    float* __restrict__ outp, float* __restrict__ attn_out) {
    int n = (blockIdx.x * 256 + threadIdx.x) >> 6;   // wave id = node
    if (n >= N_NODES) return;
    int l  = threadIdx.x & 63;
    int es = l >> 3;
    int h  = l & 7;
    int start = rowptr[n], end = rowptr[n + 1];
    float vt_h = vt[n * NH + h];

    // Phase A: denominator
    float dsum = 0.f;
    for (int p = start + es; p < end; p += 8) {
        int2 se = csr[p];
        float s = vs[se.x * NH + h] + vt_h;
        s = (s >= 0.f) ? s : 0.2f * s;
        dsum += __expf(s) / dist[se.y];
    }
    dsum += __shfl_xor(dsum, 8, 64);
    dsum += __shfl_xor(dsum, 16, 64);
    dsum += __shfl_xor(dsum, 32, 64);
    float rden = 1.f / dsum;

    // Phase B: attn write + weighted accumulate (16 channels of head h per lane)
    float acc[16];
    #pragma unroll
    for (int i = 0; i < 16; ++i) acc[i] = 0.f;
    for (int p = start + es; p < end; p += 8) {
        int2 se = csr[p];
        float s = vs[se.x * NH + h] + vt_h;
        s = (s >= 0.f) ? s : 0.2f * s;
        float attn = __expf(s) / dist[se.y] * rden;
        attn_out[(size_t)se.y * NH + h] = attn;
        const float4* vrow = (const float4*)(value + (size_t)se.x * MD + h * DV);
        #pragma unroll
        for (int i = 0; i < 4; ++i) {
            float4 v = vrow[i];
            acc[i * 4 + 0] += attn * v.x;
            acc[i * 4 + 1] += attn * v.y;
            acc[i * 4 + 2] += attn * v.z;
            acc[i * 4 + 3] += attn * v.w;
        }
    }
    #pragma unroll
    for (int i = 0; i < 16; ++i) {
        acc[i] += __shfl_xor(acc[i], 8, 64);
        acc[i] += __shfl_xor(acc[i], 16, 64);
        acc[i] += __shfl_xor(acc[i], 32, 64);
    }
    if (es == 0) {                      // lanes 0..7 = heads 0..7
        float4* orow = (float4*)(outp + (size_t)n * MD + h * DV);
        #pragma unroll
        for (int i = 0; i < 4; ++i) {
            float4 o = orow[i];
            o.x += acc[i * 4 + 0]; o.y += acc[i * 4 + 1];
            o.z += acc[i * 4 + 2]; o.w += acc[i * 4 + 3];
            orow[i] = o;
        }
    }
}

// ---------------------------------------------------------------------------
extern "C" void kernel_launch(void* const* d_in, const int* in_sizes, int n_in,
                              void* d_out, int out_size, void* d_ws, size_t ws_size,
                              hipStream_t stream) {
    const float* inp  = (const float*)d_in[0];
    const int*   ei   = (const int*)d_in[1];
    const float* dist = (const float*)d_in[2];
    const float* Wv   = (const float*)d_in[4];
    const float* wsrc = (const float*)d_in[5];
    const float* wtgt = (const float*)d_in[6];
    const float* Ws   = (const float*)d_in[7];
    const float* bias = (const float*)d_in[8];

    float* outp = (float*)d_out;
    float* attn = outp + (size_t)N_NODES * MD;

    float* wsf   = (float*)d_ws;
    float* B     = wsf;                                   // 32768
    float* value = B + 32768;                             // 6.4M
    float* vs    = value + (size_t)N_NODES * MD;          // 400k
    float* vt    = vs + N_NODES * NH;                     // 400k
    int2*  csr   = (int2*)(vt + N_NODES * NH);            // 1.6M int2 (8B-aligned)
    int*   deg    = (int*)(csr + N_EDGES);                // 50000
    int*   rowptr = deg + N_NODES;                        // 50001
    int*   boff   = rowptr + N_NODES + 1;                 // 256
    int*   cursor = boff + 256;                           // 50000

    hipMemsetAsync(deg, 0, (size_t)N_NODES * sizeof(int), stream);

    k0_prep<<<128, 256, 0, stream>>>(Wv, Ws, B);
    k1_project<<<(N_NODES + 63) / 64, 256, 0, stream>>>(inp, B, bias, value, outp);
    k2_vsvt<<<(N_NODES * NH + 255) / 256, 256, 0, stream>>>(value, wsrc, wtgt, vs, vt);
    k_hist<<<(N_EDGES + 255) / 256, 256, 0, stream>>>(ei, deg);
    k_scan1<<<SCAN_NBLK, 256, 0, stream>>>(deg, rowptr, cursor /*tmp bsum*/);
    // NOTE: k_scan1's bsum must not alias cursor's live use — bsum uses first
    // 196 ints of cursor, which k_scan3 fully overwrites afterwards. Safe.
    k_scan2<<<1, 256, 0, stream>>>(cursor /*bsum*/, boff);
    k_scan3<<<SCAN_NBLK, 256, 0, stream>>>(rowptr, boff, cursor);
    k_fill<<<(N_EDGES + 255) / 256, 256, 0, stream>>>(ei, cursor, csr);
    k_gather<<<(N_NODES + 3) / 4, 256, 0, stream>>>(csr, rowptr, dist, vs, vt,
                                                    value, outp, attn);
}

// Round 3
// 538.135 us; speedup vs baseline: 21.8554x; 1.1117x over previous
//
#include <hip/hip_runtime.h>

#define N_NODES 50000
#define N_EDGES 1600000
#define MD 128
#define NH 8
#define DV 16
#define SCAN_NBLK 196   // 196*256 = 50176 >= N_NODES

typedef unsigned int uint;
typedef unsigned short ushort;

__device__ __forceinline__ float bflo(uint u) { return __uint_as_float(u << 16); }
__device__ __forceinline__ float bfhi(uint u) { return __uint_as_float(u & 0xffff0000u); }
__device__ __forceinline__ ushort f2bf(float x) {
    uint b = __float_as_uint(x);
    b += 0x7fffu + ((b >> 16) & 1u);      // RNE
    return (ushort)(b >> 16);
}

// ---------------------------------------------------------------------------
// K0: combined transposed weight B[k][j]: j<128 -> Wv[j][k], j>=128 -> Ws[j-128][k]
// ---------------------------------------------------------------------------
__global__ void k0_prep(const float* __restrict__ Wv, const float* __restrict__ Ws,
                        float* __restrict__ B) {
    int idx = blockIdx.x * 256 + threadIdx.x;
    int k = idx >> 8;
    int j = idx & 255;
    B[idx] = (j < 128) ? Wv[j * 128 + k] : Ws[(j - 128) * 128 + k];
}

// ---------------------------------------------------------------------------
// K1: fused GEMM + epilogue:
//   value16[n][:]  = bf16(inp[n] @ Wv^T)       (c0 < 128 threads)
//   vs/vt[n][h]    = <value row, w_src/tgt>    (computed in-register)
//   outp[n][:]     = inp[n] @ Ws^T + bias      (c0 >= 128 threads)
// ---------------------------------------------------------------------------
__global__ __launch_bounds__(256) void k1_project(
    const float* __restrict__ inp, const float* __restrict__ B,
    const float* __restrict__ bias, const float* __restrict__ wsrc,
    const float* __restrict__ wtgt, ushort* __restrict__ value16,
    float* __restrict__ vs, float* __restrict__ vt, float* __restrict__ outp) {
    __shared__ float sA[64][132];
    __shared__ float sB[32][256];

    const int tid = threadIdx.x;
    const int n0  = blockIdx.x * 64;

    #pragma unroll
    for (int i = 0; i < 8; ++i) {
        int f4 = i * 256 + tid;
        int r  = f4 >> 5;
        int c4 = f4 & 31;
        float4 v = make_float4(0.f, 0.f, 0.f, 0.f);
        if (n0 + r < N_NODES) v = ((const float4*)(inp + (size_t)(n0 + r) * MD))[c4];
        sA[r][c4 * 4 + 0] = v.x; sA[r][c4 * 4 + 1] = v.y;
        sA[r][c4 * 4 + 2] = v.z; sA[r][c4 * 4 + 3] = v.w;
    }

    float acc[4][16];
    #pragma unroll
    for (int r = 0; r < 4; ++r)
        #pragma unroll
        for (int c = 0; c < 16; ++c) acc[r][c] = 0.f;

    const int r0 = (tid >> 4) * 4;
    const int c0 = (tid & 15) * 16;

    for (int kc = 0; kc < 4; ++kc) {
        #pragma unroll
        for (int i = 0; i < 8; ++i) {
            int f4 = i * 256 + tid;
            int kr = f4 >> 6;
            int c4 = f4 & 63;
            ((float4*)(&sB[kr][0]))[c4] =
                ((const float4*)(B + (size_t)(kc * 32 + kr) * 256))[c4];
        }
        __syncthreads();
        #pragma unroll 4
        for (int k = 0; k < 32; ++k) {
            float a0 = sA[r0 + 0][kc * 32 + k];
            float a1 = sA[r0 + 1][kc * 32 + k];
            float a2 = sA[r0 + 2][kc * 32 + k];
            float a3 = sA[r0 + 3][kc * 32 + k];
            float b[16];
            #pragma unroll
            for (int i = 0; i < 4; ++i) {
                float4 bv = ((const float4*)(&sB[k][c0]))[i];
                b[i * 4 + 0] = bv.x; b[i * 4 + 1] = bv.y;
                b[i * 4 + 2] = bv.z; b[i * 4 + 3] = bv.w;
            }
            #pragma unroll
            for (int c = 0; c < 16; ++c) {
                acc[0][c] = fmaf(a0, b[c], acc[0][c]);
                acc[1][c] = fmaf(a1, b[c], acc[1][c]);
                acc[2][c] = fmaf(a2, b[c], acc[2][c]);
                acc[3][c] = fmaf(a3, b[c], acc[3][c]);
            }
        }
        __syncthreads();
    }

    if (c0 < 128) {
        const int h = c0 >> 4;                  // head owned by this thread
        float wsr[16], wtr[16];
        #pragma unroll
        for (int i = 0; i < 16; ++i) { wsr[i] = wsrc[c0 + i]; wtr[i] = wtgt[c0 + i]; }
        #pragma unroll
        for (int r = 0; r < 4; ++r) {
            int n = n0 + r0 + r;
            if (n >= N_NODES) continue;
            union { ushort u[16]; uint4 q[2]; } pk;
            float s = 0.f, t = 0.f;
            #pragma unroll
            for (int i = 0; i < 16; ++i) {
                float v = acc[r][i];
                pk.u[i] = f2bf(v);
                s = fmaf(v, wsr[i], s);
                t = fmaf(v, wtr[i], t);
            }
            uint4* dst = (uint4*)(value16 + (size_t)n * MD + c0);
            dst[0] = pk.q[0]; dst[1] = pk.q[1];
            vs[n * NH + h] = s;
            vt[n * NH + h] = t;
        }
    } else {
        const int cc = c0 - 128;
        #pragma unroll
        for (int r = 0; r < 4; ++r) {
            int n = n0 + r0 + r;
            if (n >= N_NODES) continue;
            float4* dst = (float4*)(outp + (size_t)n * MD + cc);
            #pragma unroll
            for (int i = 0; i < 4; ++i)
                dst[i] = make_float4(acc[r][i * 4 + 0] + bias[cc + i * 4 + 0],
                                     acc[r][i * 4 + 1] + bias[cc + i * 4 + 1],
                                     acc[r][i * 4 + 2] + bias[cc + i * 4 + 2],
                                     acc[r][i * 4 + 3] + bias[cc + i * 4 + 3]);
        }
    }
}

// ---------------------------------------------------------------------------
// CSR build: histogram -> hierarchical scan -> fill (int4-vectorized)
// ---------------------------------------------------------------------------
__global__ void k_hist(const int* __restrict__ ei, int* __restrict__ deg) {
    int i = blockIdx.x * 256 + threadIdx.x;           // 4 edges / thread
    if (i >= N_EDGES / 4) return;
    int4 t = ((const int4*)(ei + N_EDGES))[i];
    atomicAdd(&deg[t.x], 1);
    atomicAdd(&deg[t.y], 1);
    atomicAdd(&deg[t.z], 1);
    atomicAdd(&deg[t.w], 1);
}

__global__ void k_scan1(const int* __restrict__ deg, int* __restrict__ rowptr,
                        int* __restrict__ bsum) {
    __shared__ int s[256];
    int t = threadIdx.x, i = blockIdx.x * 256 + t;
    int v = (i < N_NODES) ? deg[i] : 0;
    s[t] = v;
    __syncthreads();
    #pragma unroll
    for (int off = 1; off < 256; off <<= 1) {
        int x = (t >= off) ? s[t - off] : 0;
        __syncthreads();
        s[t] += x;
        __syncthreads();
    }
    if (i < N_NODES) rowptr[i] = s[t] - v;
    if (t == 255) bsum[blockIdx.x] = s[255];
}

__global__ void k_scan2(int* __restrict__ bsum, int* __restrict__ boff) {
    __shared__ int s[256];
    int t = threadIdx.x;
    int v = (t < SCAN_NBLK) ? bsum[t] : 0;
    s[t] = v;
    __syncthreads();
    #pragma unroll
    for (int off = 1; off < 256; off <<= 1) {
        int x = (t >= off) ? s[t - off] : 0;
        __syncthreads();
        s[t] += x;
        __syncthreads();
    }
    if (t < SCAN_NBLK) boff[t] = s[t] - v;
}

__global__ void k_scan3(int* __restrict__ rowptr, const int* __restrict__ boff,
                        int* __restrict__ cursor) {
    int i = blockIdx.x * 256 + threadIdx.x;
    if (i < N_NODES) {
        int r = rowptr[i] + boff[blockIdx.x];
        rowptr[i] = r;
        cursor[i] = r;
    }
    if (i == 0) rowptr[N_NODES] = N_EDGES;
}

__global__ void k_fill(const int* __restrict__ ei, int* __restrict__ cursor,
                       int2* __restrict__ csr) {
    int i = blockIdx.x * 256 + threadIdx.x;           // 4 edges / thread
    if (i >= N_EDGES / 4) return;
    int4 s = ((const int4*)ei)[i];
    int4 t = ((const int4*)(ei + N_EDGES))[i];
    int e = i * 4;
    int p0 = atomicAdd(&cursor[t.x], 1); csr[p0] = make_int2(s.x, e + 0);
    int p1 = atomicAdd(&cursor[t.y], 1); csr[p1] = make_int2(s.y, e + 1);
    int p2 = atomicAdd(&cursor[t.z], 1); csr[p2] = make_int2(s.z, e + 2);
    int p3 = atomicAdd(&cursor[t.w], 1); csr[p3] = make_int2(s.w, e + 3);
}

// ---------------------------------------------------------------------------
// K_GATHER: one wave per target node. Lane l: es = l>>3, h = l&7.
// Phase A: per-head denom (butterfly over es). Phase B: attn write +
// 16-channel bf16-value accumulation, cross-lane reduce, one RMW per node.
// ---------------------------------------------------------------------------
__global__ __launch_bounds__(256) void k_gather(
    const int2* __restrict__ csr, const int* __restrict__ rowptr,
    const float* __restrict__ dist, const float* __restrict__ vs,
    const float* __restrict__ vt, const ushort* __restrict__ value16,
    float* __restrict__ outp, float* __restrict__ attn_out) {
    int n = (blockIdx.x * 256 + threadIdx.x) >> 6;
    if (n >= N_NODES) return;
    int l  = threadIdx.x & 63;
    int es = l >> 3;
    int h  = l & 7;
    int start = rowptr[n], end = rowptr[n + 1];
    float vt_h = vt[n * NH + h];

    // Phase A: denominator
    float dsum = 0.f;
    for (int p = start + es; p < end; p += 8) {
        int2 se = csr[p];
        float s = vs[se.x * NH + h] + vt_h;
        s = (s >= 0.f) ? s : 0.2f * s;
        dsum += __expf(s) / dist[se.y];
    }
    dsum += __shfl_xor(dsum, 8, 64);
    dsum += __shfl_xor(dsum, 16, 64);
    dsum += __shfl_xor(dsum, 32, 64);
    float rden = 1.f / dsum;

    // Phase B
    float acc[16];
    #pragma unroll
    for (int i = 0; i < 16; ++i) acc[i] = 0.f;
    for (int p = start + es; p < end; p += 8) {
        int2 se = csr[p];
        float s = vs[se.x * NH + h] + vt_h;
        s = (s >= 0.f) ? s : 0.2f * s;
        float attn = __expf(s) / dist[se.y] * rden;
        attn_out[(size_t)se.y * NH + h] = attn;
        const uint4* vrow = (const uint4*)(value16 + (size_t)se.x * MD + h * DV);
        uint4 q0 = vrow[0], q1 = vrow[1];
        acc[0]  += attn * bflo(q0.x); acc[1]  += attn * bfhi(q0.x);
        acc[2]  += attn * bflo(q0.y); acc[3]  += attn * bfhi(q0.y);
        acc[4]  += attn * bflo(q0.z); acc[5]  += attn * bfhi(q0.z);
        acc[6]  += attn * bflo(q0.w); acc[7]  += attn * bfhi(q0.w);
        acc[8]  += attn * bflo(q1.x); acc[9]  += attn * bfhi(q1.x);
        acc[10] += attn * bflo(q1.y); acc[11] += attn * bfhi(q1.y);
        acc[12] += attn * bflo(q1.z); acc[13] += attn * bfhi(q1.z);
        acc[14] += attn * bflo(q1.w); acc[15] += attn * bfhi(q1.w);
    }
    #pragma unroll
    for (int i = 0; i < 16; ++i) {
        acc[i] += __shfl_xor(acc[i], 8, 64);
        acc[i] += __shfl_xor(acc[i], 16, 64);
        acc[i] += __shfl_xor(acc[i], 32, 64);
    }
    if (es == 0) {
        float4* orow = (float4*)(outp + (size_t)n * MD + h * DV);
        #pragma unroll
        for (int i = 0; i < 4; ++i) {
            float4 o = orow[i];
            o.x += acc[i * 4 + 0]; o.y += acc[i * 4 + 1];
            o.z += acc[i * 4 + 2]; o.w += acc[i * 4 + 3];
            orow[i] = o;
        }
    }
}

// ---------------------------------------------------------------------------
extern "C" void kernel_launch(void* const* d_in, const int* in_sizes, int n_in,
                              void* d_out, int out_size, void* d_ws, size_t ws_size,
                              hipStream_t stream) {
    const float* inp  = (const float*)d_in[0];
    const int*   ei   = (const int*)d_in[1];
    const float* dist = (const float*)d_in[2];
    const float* Wv   = (const float*)d_in[4];
    const float* wsrc = (const float*)d_in[5];
    const float* wtgt = (const float*)d_in[6];
    const float* Ws   = (const float*)d_in[7];
    const float* bias = (const float*)d_in[8];

    float* outp = (float*)d_out;
    float* attn = outp + (size_t)N_NODES * MD;

    float*  wsf     = (float*)d_ws;
    float*  B       = wsf;                                  // 32768 f
    float*  vs      = B + 32768;                            // 400k f
    float*  vt      = vs + N_NODES * NH;                    // 400k f
    ushort* value16 = (ushort*)(vt + N_NODES * NH);         // N*128 bf16 (12.8MB)
    int2*   csr     = (int2*)(value16 + (size_t)N_NODES * MD); // 1.6M int2
    int*    deg     = (int*)(csr + N_EDGES);                // 50000
    int*    rowptr  = deg + N_NODES;                        // 50001
    int*    boff    = rowptr + N_NODES + 1;                 // 256
    int*    cursor  = boff + 256;                           // 50000

    hipMemsetAsync(deg, 0, (size_t)N_NODES * sizeof(int), stream);

    k0_prep<<<128, 256, 0, stream>>>(Wv, Ws, B);
    k1_project<<<(N_NODES + 63) / 64, 256, 0, stream>>>(inp, B, bias, wsrc, wtgt,
                                                        value16, vs, vt, outp);
    k_hist<<<(N_EDGES / 4 + 255) / 256, 256, 0, stream>>>(ei, deg);
    k_scan1<<<SCAN_NBLK, 256, 0, stream>>>(deg, rowptr, cursor /*tmp bsum*/);
    k_scan2<<<1, 256, 0, stream>>>(cursor /*bsum*/, boff);
    k_scan3<<<SCAN_NBLK, 256, 0, stream>>>(rowptr, boff, cursor);
    k_fill<<<(N_EDGES / 4 + 255) / 256, 256, 0, stream>>>(ei, cursor, csr);
    k_gather<<<(N_NODES + 3) / 4, 256, 0, stream>>>(csr, rowptr, dist, vs, vt,
                                                    value16, outp, attn);
}

// Round 4
// 419.551 us; speedup vs baseline: 28.0328x; 1.2826x over previous
//
#include <hip/hip_runtime.h>

#define N_NODES 50000
#define N_EDGES 1600000
#define MD 128
#define NH 8
#define DV 16
#define SCAN_NBLK 196   // 196*256 = 50176 >= N_NODES

typedef unsigned int uint;
typedef unsigned short ushort;

__device__ __forceinline__ float bflo(uint u) { return __uint_as_float(u << 16); }
__device__ __forceinline__ float bfhi(uint u) { return __uint_as_float(u & 0xffff0000u); }
__device__ __forceinline__ ushort f2bf(float x) {
    uint b = __float_as_uint(x);
    b += 0x7fffu + ((b >> 16) & 1u);      // RNE
    return (ushort)(b >> 16);
}

// ---------------------------------------------------------------------------
// K0: combined transposed weight B[k][j]: j<128 -> Wv[j][k], j>=128 -> Ws[j-128][k]
// ---------------------------------------------------------------------------
__global__ void k0_prep(const float* __restrict__ Wv, const float* __restrict__ Ws,
                        float* __restrict__ B) {
    int idx = blockIdx.x * 256 + threadIdx.x;
    int k = idx >> 8;
    int j = idx & 255;
    B[idx] = (j < 128) ? Wv[j * 128 + k] : Ws[(j - 128) * 128 + k];
}

// ---------------------------------------------------------------------------
// K1: fused GEMM + epilogue.
// Thread map: r0=(tid&15)*4 rows, c0=(tid>>4)*16 cols.
//   sA row stride 129 -> a-reads 2-way (free); sB b128 reads 2-way (free).
// ---------------------------------------------------------------------------
__global__ __launch_bounds__(256) void k1_project(
    const float* __restrict__ inp, const float* __restrict__ B,
    const float* __restrict__ bias, const float* __restrict__ wsrc,
    const float* __restrict__ wtgt, ushort* __restrict__ value16,
    float* __restrict__ vs, float* __restrict__ vt, float* __restrict__ outp) {
    __shared__ float sA[64 * 129];     // stride 129: 4-row lane stride -> 2-way
    __shared__ float sB[32][256];

    const int tid = threadIdx.x;
    const int n0  = blockIdx.x * 64;

    #pragma unroll
    for (int i = 0; i < 8; ++i) {
        int f4 = i * 256 + tid;
        int r  = f4 >> 5;
        int c4 = f4 & 31;
        float4 v = make_float4(0.f, 0.f, 0.f, 0.f);
        if (n0 + r < N_NODES) v = ((const float4*)(inp + (size_t)(n0 + r) * MD))[c4];
        sA[r * 129 + c4 * 4 + 0] = v.x;
        sA[r * 129 + c4 * 4 + 1] = v.y;
        sA[r * 129 + c4 * 4 + 2] = v.z;
        sA[r * 129 + c4 * 4 + 3] = v.w;
    }

    float acc[4][16];
    #pragma unroll
    for (int r = 0; r < 4; ++r)
        #pragma unroll
        for (int c = 0; c < 16; ++c) acc[r][c] = 0.f;

    const int r0 = (tid & 15) * 4;
    const int c0 = (tid >> 4) * 16;

    for (int kc = 0; kc < 4; ++kc) {
        #pragma unroll
        for (int i = 0; i < 8; ++i) {
            int f4 = i * 256 + tid;
            int kr = f4 >> 6;
            int c4 = f4 & 63;
            ((float4*)(&sB[kr][0]))[c4] =
                ((const float4*)(B + (size_t)(kc * 32 + kr) * 256))[c4];
        }
        __syncthreads();
        #pragma unroll 4
        for (int k = 0; k < 32; ++k) {
            int kk = kc * 32 + k;
            float a0 = sA[(r0 + 0) * 129 + kk];
            float a1 = sA[(r0 + 1) * 129 + kk];
            float a2 = sA[(r0 + 2) * 129 + kk];
            float a3 = sA[(r0 + 3) * 129 + kk];
            float b[16];
            #pragma unroll
            for (int i = 0; i < 4; ++i) {
                float4 bv = ((const float4*)(&sB[k][c0]))[i];
                b[i * 4 + 0] = bv.x; b[i * 4 + 1] = bv.y;
                b[i * 4 + 2] = bv.z; b[i * 4 + 3] = bv.w;
            }
            #pragma unroll
            for (int c = 0; c < 16; ++c) {
                acc[0][c] = fmaf(a0, b[c], acc[0][c]);
                acc[1][c] = fmaf(a1, b[c], acc[1][c]);
                acc[2][c] = fmaf(a2, b[c], acc[2][c]);
                acc[3][c] = fmaf(a3, b[c], acc[3][c]);
            }
        }
        __syncthreads();
    }

    if (c0 < 128) {
        const int h = c0 >> 4;
        float wsr[16], wtr[16];
        #pragma unroll
        for (int i = 0; i < 16; ++i) { wsr[i] = wsrc[c0 + i]; wtr[i] = wtgt[c0 + i]; }
        #pragma unroll
        for (int r = 0; r < 4; ++r) {
            int n = n0 + r0 + r;
            if (n >= N_NODES) continue;
            union { ushort u[16]; uint4 q[2]; } pk;
            float s = 0.f, t = 0.f;
            #pragma unroll
            for (int i = 0; i < 16; ++i) {
                float v = acc[r][i];
                pk.u[i] = f2bf(v);
                s = fmaf(v, wsr[i], s);
                t = fmaf(v, wtr[i], t);
            }
            uint4* dst = (uint4*)(value16 + (size_t)n * MD + c0);
            dst[0] = pk.q[0]; dst[1] = pk.q[1];
            vs[n * NH + h] = s;
            vt[n * NH + h] = t;
        }
    } else {
        const int cc = c0 - 128;
        #pragma unroll
        for (int r = 0; r < 4; ++r) {
            int n = n0 + r0 + r;
            if (n >= N_NODES) continue;
            float4* dst = (float4*)(outp + (size_t)n * MD + cc);
            #pragma unroll
            for (int i = 0; i < 4; ++i)
                dst[i] = make_float4(acc[r][i * 4 + 0] + bias[cc + i * 4 + 0],
                                     acc[r][i * 4 + 1] + bias[cc + i * 4 + 1],
                                     acc[r][i * 4 + 2] + bias[cc + i * 4 + 2],
                                     acc[r][i * 4 + 3] + bias[cc + i * 4 + 3]);
        }
    }
}

// ---------------------------------------------------------------------------
// CSR build: one atomic pass (slot = fetch_add(deg[tgt])) -> scan -> place
// ---------------------------------------------------------------------------
__global__ void k_slot(const int* __restrict__ ei, int* __restrict__ deg,
                       ushort* __restrict__ slot16) {
    int i = blockIdx.x * 256 + threadIdx.x;            // 4 edges / thread
    if (i >= N_EDGES / 4) return;
    int4 t = ((const int4*)(ei + N_EDGES))[i];
    ushort4 s;
    s.x = (ushort)atomicAdd(&deg[t.x], 1);
    s.y = (ushort)atomicAdd(&deg[t.y], 1);
    s.z = (ushort)atomicAdd(&deg[t.z], 1);
    s.w = (ushort)atomicAdd(&deg[t.w], 1);
    ((ushort4*)slot16)[i] = s;
}

__global__ void k_scan1(const int* __restrict__ deg, int* __restrict__ rowptr,
                        int* __restrict__ bsum) {
    __shared__ int s[256];
    int t = threadIdx.x, i = blockIdx.x * 256 + t;
    int v = (i < N_NODES) ? deg[i] : 0;
    s[t] = v;
    __syncthreads();
    #pragma unroll
    for (int off = 1; off < 256; off <<= 1) {
        int x = (t >= off) ? s[t - off] : 0;
        __syncthreads();
        s[t] += x;
        __syncthreads();
    }
    if (i < N_NODES) rowptr[i] = s[t] - v;
    if (t == 255) bsum[blockIdx.x] = s[255];
}

__global__ void k_scan2(const int* __restrict__ bsum, int* __restrict__ boff) {
    __shared__ int s[256];
    int t = threadIdx.x;
    int v = (t < SCAN_NBLK) ? bsum[t] : 0;
    s[t] = v;
    __syncthreads();
    #pragma unroll
    for (int off = 1; off < 256; off <<= 1) {
        int x = (t >= off) ? s[t - off] : 0;
        __syncthreads();
        s[t] += x;
        __syncthreads();
    }
    if (t < SCAN_NBLK) boff[t] = s[t] - v;
}

__global__ void k_scan3(int* __restrict__ rowptr, const int* __restrict__ boff) {
    int i = blockIdx.x * 256 + threadIdx.x;
    if (i < N_NODES) rowptr[i] += boff[blockIdx.x];
    if (i == 0) rowptr[N_NODES] = N_EDGES;
}

__global__ void k_place(const int* __restrict__ ei, const int* __restrict__ rowptr,
                        const ushort* __restrict__ slot16, int2* __restrict__ csr) {
    int i = blockIdx.x * 256 + threadIdx.x;            // 4 edges / thread
    if (i >= N_EDGES / 4) return;
    int4 s = ((const int4*)ei)[i];
    int4 t = ((const int4*)(ei + N_EDGES))[i];
    ushort4 sl = ((const ushort4*)slot16)[i];
    int e = i * 4;
    csr[rowptr[t.x] + sl.x] = make_int2(s.x, e + 0);
    csr[rowptr[t.y] + sl.y] = make_int2(s.y, e + 1);
    csr[rowptr[t.z] + sl.z] = make_int2(s.z, e + 2);
    csr[rowptr[t.w] + sl.w] = make_int2(s.w, e + 3);
}

// ---------------------------------------------------------------------------
// K_GATHER: one wave per target node. Lane l: es = l>>3, h = l&7.
// ---------------------------------------------------------------------------
__global__ __launch_bounds__(256) void k_gather(
    const int2* __restrict__ csr, const int* __restrict__ rowptr,
    const float* __restrict__ dist, const float* __restrict__ vs,
    const float* __restrict__ vt, const ushort* __restrict__ value16,
    float* __restrict__ outp, float* __restrict__ attn_out) {
    int n = (blockIdx.x * 256 + threadIdx.x) >> 6;
    if (n >= N_NODES) return;
    int l  = threadIdx.x & 63;
    int es = l >> 3;
    int h  = l & 7;
    int start = rowptr[n], end = rowptr[n + 1];
    float vt_h = vt[n * NH + h];

    // Phase A: denominator
    float dsum = 0.f;
    for (int p = start + es; p < end; p += 8) {
        int2 se = csr[p];
        float s = vs[se.x * NH + h] + vt_h;
        s = (s >= 0.f) ? s : 0.2f * s;
        dsum += __expf(s) / dist[se.y];
    }
    dsum += __shfl_xor(dsum, 8, 64);
    dsum += __shfl_xor(dsum, 16, 64);
    dsum += __shfl_xor(dsum, 32, 64);
    float rden = 1.f / dsum;

    // Phase B
    float acc[16];
    #pragma unroll
    for (int i = 0; i < 16; ++i) acc[i] = 0.f;
    for (int p = start + es; p < end; p += 8) {
        int2 se = csr[p];
        float s = vs[se.x * NH + h] + vt_h;
        s = (s >= 0.f) ? s : 0.2f * s;
        float attn = __expf(s) / dist[se.y] * rden;
        attn_out[(size_t)se.y * NH + h] = attn;
        const uint4* vrow = (const uint4*)(value16 + (size_t)se.x * MD + h * DV);
        uint4 q0 = vrow[0], q1 = vrow[1];
        acc[0]  += attn * bflo(q0.x); acc[1]  += attn * bfhi(q0.x);
        acc[2]  += attn * bflo(q0.y); acc[3]  += attn * bfhi(q0.y);
        acc[4]  += attn * bflo(q0.z); acc[5]  += attn * bfhi(q0.z);
        acc[6]  += attn * bflo(q0.w); acc[7]  += attn * bfhi(q0.w);
        acc[8]  += attn * bflo(q1.x); acc[9]  += attn * bfhi(q1.x);
        acc[10] += attn * bflo(q1.y); acc[11] += attn * bfhi(q1.y);
        acc[12] += attn * bflo(q1.z); acc[13] += attn * bfhi(q1.z);
        acc[14] += attn * bflo(q1.w); acc[15] += attn * bfhi(q1.w);
    }
    #pragma unroll
    for (int i = 0; i < 16; ++i) {
        acc[i] += __shfl_xor(acc[i], 8, 64);
        acc[i] += __shfl_xor(acc[i], 16, 64);
        acc[i] += __shfl_xor(acc[i], 32, 64);
    }
    if (es == 0) {
        float4* orow = (float4*)(outp + (size_t)n * MD + h * DV);
        #pragma unroll
        for (int i = 0; i < 4; ++i) {
            float4 o = orow[i];
            o.x += acc[i * 4 + 0]; o.y += acc[i * 4 + 1];
            o.z += acc[i * 4 + 2]; o.w += acc[i * 4 + 3];
            orow[i] = o;
        }
    }
}

// ---------------------------------------------------------------------------
extern "C" void kernel_launch(void* const* d_in, const int* in_sizes, int n_in,
                              void* d_out, int out_size, void* d_ws, size_t ws_size,
                              hipStream_t stream) {
    const float* inp  = (const float*)d_in[0];
    const int*   ei   = (const int*)d_in[1];
    const float* dist = (const float*)d_in[2];
    const float* Wv   = (const float*)d_in[4];
    const float* wsrc = (const float*)d_in[5];
    const float* wtgt = (const float*)d_in[6];
    const float* Ws   = (const float*)d_in[7];
    const float* bias = (const float*)d_in[8];

    float* outp = (float*)d_out;
    float* attn = outp + (size_t)N_NODES * MD;

    float*  wsf     = (float*)d_ws;
    float*  B       = wsf;                                     // 32768 f
    float*  vs      = B + 32768;                               // 400k f
    float*  vt      = vs + N_NODES * NH;                       // 400k f
    ushort* value16 = (ushort*)(vt + N_NODES * NH);            // 12.8 MB
    int2*   csr     = (int2*)(value16 + (size_t)N_NODES * MD); // 12.8 MB
    ushort* slot16  = (ushort*)(csr + N_EDGES);                // 3.2 MB
    int*    deg     = (int*)(slot16 + N_EDGES);                // 50000
    int*    rowptr  = deg + N_NODES;                           // 50001
    int*    bsum    = rowptr + N_NODES + 1;                    // 256
    int*    boff    = bsum + 256;                              // 256

    hipMemsetAsync(deg, 0, (size_t)N_NODES * sizeof(int), stream);

    k0_prep<<<128, 256, 0, stream>>>(Wv, Ws, B);
    k1_project<<<(N_NODES + 63) / 64, 256, 0, stream>>>(inp, B, bias, wsrc, wtgt,
                                                        value16, vs, vt, outp);
    k_slot<<<(N_EDGES / 4 + 255) / 256, 256, 0, stream>>>(ei, deg, slot16);
    k_scan1<<<SCAN_NBLK, 256, 0, stream>>>(deg, rowptr, bsum);
    k_scan2<<<1, 256, 0, stream>>>(bsum, boff);
    k_scan3<<<SCAN_NBLK, 256, 0, stream>>>(rowptr, boff);
    k_place<<<(N_EDGES / 4 + 255) / 256, 256, 0, stream>>>(ei, rowptr, slot16, csr);
    k_gather<<<(N_NODES + 3) / 4, 256, 0, stream>>>(csr, rowptr, dist, vs, vt,
                                                    value16, outp, attn);
}

// Round 5
// 372.065 us; speedup vs baseline: 31.6105x; 1.1276x over previous
//
#include <hip/hip_runtime.h>

#define N_NODES 50000
#define N_EDGES 1600000
#define MD 128
#define NH 8
#define DV 16
#define SCAN_NBLK 196      // 196*256 = 50176 >= N_NODES
#define GEMM_NBLK 782      // ceil(50000/64)
#define SLOT_NBLK 1563     // ceil(400000/256)  (400000 = N_EDGES/4)

typedef unsigned int uint;
typedef unsigned short ushort;

__device__ __forceinline__ float bflo(uint u) { return __uint_as_float(u << 16); }
__device__ __forceinline__ float bfhi(uint u) { return __uint_as_float(u & 0xffff0000u); }
__device__ __forceinline__ ushort f2bf(float x) {
    uint b = __float_as_uint(x);
    b += 0x7fffu + ((b >> 16) & 1u);      // RNE
    return (ushort)(b >> 16);
}

// ---------------------------------------------------------------------------
// K0: combined transposed weight B[k][j]: j<128 -> Wv[j][k], j>=128 -> Ws[j-128][k]
// ---------------------------------------------------------------------------
__global__ void k0_prep(const float* __restrict__ Wv, const float* __restrict__ Ws,
                        float* __restrict__ B) {
    int idx = blockIdx.x * 256 + threadIdx.x;
    int k = idx >> 8;
    int j = idx & 255;
    B[idx] = (j < 128) ? Wv[j * 128 + k] : Ws[(j - 128) * 128 + k];
}

// ---------------------------------------------------------------------------
// K_FRONT: interleaved fusion of the GEMM (k1) and the CSR slot pass.
//   b%3==0 -> GEMM block b/3 ; else slot block (b - b/3 - 1).
// GEMM blocks are VALU-bound, slot blocks are atomic-latency-bound: they
// co-schedule on a CU, hiding the GEMM behind the atomic pass.
// ---------------------------------------------------------------------------
__global__ __launch_bounds__(256) void k_front(
    const float* __restrict__ inp, const float* __restrict__ B,
    const float* __restrict__ bias, const float* __restrict__ wsrc,
    const float* __restrict__ wtgt, ushort* __restrict__ value16,
    float* __restrict__ vs, float* __restrict__ vt, float* __restrict__ outp,
    const int* __restrict__ ei, int* __restrict__ deg, ushort* __restrict__ slot16) {
    __shared__ float sA[64 * 129];
    __shared__ float sB[32][256];

    const int b   = blockIdx.x;
    const int tid = threadIdx.x;

    if (b % 3 != 0) {
        // ---- slot pass: one returning atomic per edge ----
        int slotId = b - b / 3 - 1;
        int i = slotId * 256 + tid;               // 4 edges / thread
        if (i >= N_EDGES / 4) return;
        int4 t = ((const int4*)(ei + N_EDGES))[i];
        ushort4 s;
        s.x = (ushort)atomicAdd(&deg[t.x], 1);
        s.y = (ushort)atomicAdd(&deg[t.y], 1);
        s.z = (ushort)atomicAdd(&deg[t.z], 1);
        s.w = (ushort)atomicAdd(&deg[t.w], 1);
        ((ushort4*)slot16)[i] = s;
        return;
    }

    // ---- GEMM block ----
    const int n0 = (b / 3) * 64;

    #pragma unroll
    for (int i = 0; i < 8; ++i) {
        int f4 = i * 256 + tid;
        int r  = f4 >> 5;
        int c4 = f4 & 31;
        float4 v = make_float4(0.f, 0.f, 0.f, 0.f);
        if (n0 + r < N_NODES) v = ((const float4*)(inp + (size_t)(n0 + r) * MD))[c4];
        sA[r * 129 + c4 * 4 + 0] = v.x;
        sA[r * 129 + c4 * 4 + 1] = v.y;
        sA[r * 129 + c4 * 4 + 2] = v.z;
        sA[r * 129 + c4 * 4 + 3] = v.w;
    }

    float acc[4][16];
    #pragma unroll
    for (int r = 0; r < 4; ++r)
        #pragma unroll
        for (int c = 0; c < 16; ++c) acc[r][c] = 0.f;

    const int r0 = (tid & 15) * 4;
    const int c0 = (tid >> 4) * 16;

    for (int kc = 0; kc < 4; ++kc) {
        #pragma unroll
        for (int i = 0; i < 8; ++i) {
            int f4 = i * 256 + tid;
            int kr = f4 >> 6;
            int c4 = f4 & 63;
            ((float4*)(&sB[kr][0]))[c4] =
                ((const float4*)(B + (size_t)(kc * 32 + kr) * 256))[c4];
        }
        __syncthreads();
        #pragma unroll 4
        for (int k = 0; k < 32; ++k) {
            int kk = kc * 32 + k;
            float a0 = sA[(r0 + 0) * 129 + kk];
            float a1 = sA[(r0 + 1) * 129 + kk];
            float a2 = sA[(r0 + 2) * 129 + kk];
            float a3 = sA[(r0 + 3) * 129 + kk];
            float bb[16];
            #pragma unroll
            for (int i = 0; i < 4; ++i) {
                float4 bv = ((const float4*)(&sB[k][c0]))[i];
                bb[i * 4 + 0] = bv.x; bb[i * 4 + 1] = bv.y;
                bb[i * 4 + 2] = bv.z; bb[i * 4 + 3] = bv.w;
            }
            #pragma unroll
            for (int c = 0; c < 16; ++c) {
                acc[0][c] = fmaf(a0, bb[c], acc[0][c]);
                acc[1][c] = fmaf(a1, bb[c], acc[1][c]);
                acc[2][c] = fmaf(a2, bb[c], acc[2][c]);
                acc[3][c] = fmaf(a3, bb[c], acc[3][c]);
            }
        }
        __syncthreads();
    }

    if (c0 < 128) {
        const int h = c0 >> 4;
        float wsr[16], wtr[16];
        #pragma unroll
        for (int i = 0; i < 16; ++i) { wsr[i] = wsrc[c0 + i]; wtr[i] = wtgt[c0 + i]; }
        #pragma unroll
        for (int r = 0; r < 4; ++r) {
            int n = n0 + r0 + r;
            if (n >= N_NODES) continue;
            union { ushort u[16]; uint4 q[2]; } pk;
            float s = 0.f, t = 0.f;
            #pragma unroll
            for (int i = 0; i < 16; ++i) {
                float v = acc[r][i];
                pk.u[i] = f2bf(v);
                s = fmaf(v, wsr[i], s);
                t = fmaf(v, wtr[i], t);
            }
            uint4* dst = (uint4*)(value16 + (size_t)n * MD + c0);
            dst[0] = pk.q[0]; dst[1] = pk.q[1];
            vs[n * NH + h] = s;
            vt[n * NH + h] = t;
        }
    } else {
        const int cc = c0 - 128;
        #pragma unroll
        for (int r = 0; r < 4; ++r) {
            int n = n0 + r0 + r;
            if (n >= N_NODES) continue;
            float4* dst = (float4*)(outp + (size_t)n * MD + cc);
            #pragma unroll
            for (int i = 0; i < 4; ++i)
                dst[i] = make_float4(acc[r][i * 4 + 0] + bias[cc + i * 4 + 0],
                                     acc[r][i * 4 + 1] + bias[cc + i * 4 + 1],
                                     acc[r][i * 4 + 2] + bias[cc + i * 4 + 2],
                                     acc[r][i * 4 + 3] + bias[cc + i * 4 + 3]);
        }
    }
}

// ---------------------------------------------------------------------------
// Scans (exclusive prefix over deg -> rowptr)
// ---------------------------------------------------------------------------
__global__ void k_scan1(const int* __restrict__ deg, int* __restrict__ rowptr,
                        int* __restrict__ bsum) {
    __shared__ int s[256];
    int t = threadIdx.x, i = blockIdx.x * 256 + t;
    int v = (i < N_NODES) ? deg[i] : 0;
    s[t] = v;
    __syncthreads();
    #pragma unroll
    for (int off = 1; off < 256; off <<= 1) {
        int x = (t >= off) ? s[t - off] : 0;
        __syncthreads();
        s[t] += x;
        __syncthreads();
    }
    if (i < N_NODES) rowptr[i] = s[t] - v;
    if (t == 255) bsum[blockIdx.x] = s[255];
}

__global__ void k_scan2(const int* __restrict__ bsum, int* __restrict__ boff) {
    __shared__ int s[256];
    int t = threadIdx.x;
    int v = (t < SCAN_NBLK) ? bsum[t] : 0;
    s[t] = v;
    __syncthreads();
    #pragma unroll
    for (int off = 1; off < 256; off <<= 1) {
        int x = (t >= off) ? s[t - off] : 0;
        __syncthreads();
        s[t] += x;
        __syncthreads();
    }
    if (t < SCAN_NBLK) boff[t] = s[t] - v;
}

__global__ void k_scan3(int* __restrict__ rowptr, const int* __restrict__ boff) {
    int i = blockIdx.x * 256 + threadIdx.x;
    if (i < N_NODES) rowptr[i] += boff[blockIdx.x];
    if (i == 0) rowptr[N_NODES] = N_EDGES;
}

// ---------------------------------------------------------------------------
// K_PLACE: pos = rowptr[tgt] + slot; csr[pos]=(src,eid); fdist[pos]=1/dist[eid]
// ---------------------------------------------------------------------------
__global__ void k_place(const int* __restrict__ ei, const int* __restrict__ rowptr,
                        const ushort* __restrict__ slot16, const float* __restrict__ dist,
                        int2* __restrict__ csr, float* __restrict__ fdist) {
    int i = blockIdx.x * 256 + threadIdx.x;            // 4 edges / thread
    if (i >= N_EDGES / 4) return;
    int4 s = ((const int4*)ei)[i];
    int4 t = ((const int4*)(ei + N_EDGES))[i];
    ushort4 sl = ((const ushort4*)slot16)[i];
    float4 d = ((const float4*)dist)[i];
    int e = i * 4;
    int p0 = rowptr[t.x] + sl.x; csr[p0] = make_int2(s.x, e + 0); fdist[p0] = 1.f / d.x;
    int p1 = rowptr[t.y] + sl.y; csr[p1] = make_int2(s.y, e + 1); fdist[p1] = 1.f / d.y;
    int p2 = rowptr[t.z] + sl.z; csr[p2] = make_int2(s.z, e + 2); fdist[p2] = 1.f / d.z;
    int p3 = rowptr[t.w] + sl.w; csr[p3] = make_int2(s.w, e + 3); fdist[p3] = 1.f / d.w;
}

// ---------------------------------------------------------------------------
// K_GATHER: one wave per target node. Lane l: es = l>>3, h = l&7.
// ---------------------------------------------------------------------------
__global__ __launch_bounds__(256) void k_gather(
    const int2* __restrict__ csr, const int* __restrict__ rowptr,
    const float* __restrict__ fdist, const float* __restrict__ vs,
    const float* __restrict__ vt, const ushort* __restrict__ value16,
    float* __restrict__ outp, float* __restrict__ attn_out) {
    int n = (blockIdx.x * 256 + threadIdx.x) >> 6;
    if (n >= N_NODES) return;
    int l  = threadIdx.x & 63;
    int es = l >> 3;
    int h  = l & 7;
    int start = rowptr[n], end = rowptr[n + 1];
    float vt_h = vt[n * NH + h];

    // Phase A: denominator
    float dsum = 0.f;
    for (int p = start + es; p < end; p += 8) {
        int2 se = csr[p];
        float s = vs[se.x * NH + h] + vt_h;
        s = (s >= 0.f) ? s : 0.2f * s;
        dsum += __expf(s) * fdist[p];
    }
    dsum += __shfl_xor(dsum, 8, 64);
    dsum += __shfl_xor(dsum, 16, 64);
    dsum += __shfl_xor(dsum, 32, 64);
    float rden = 1.f / dsum;

    // Phase B
    float acc[16];
    #pragma unroll
    for (int i = 0; i < 16; ++i) acc[i] = 0.f;
    for (int p = start + es; p < end; p += 8) {
        int2 se = csr[p];
        float s = vs[se.x * NH + h] + vt_h;
        s = (s >= 0.f) ? s : 0.2f * s;
        float attn = __expf(s) * fdist[p] * rden;
        attn_out[(size_t)se.y * NH + h] = attn;
        const uint4* vrow = (const uint4*)(value16 + (size_t)se.x * MD + h * DV);
        uint4 q0 = vrow[0], q1 = vrow[1];
        acc[0]  += attn * bflo(q0.x); acc[1]  += attn * bfhi(q0.x);
        acc[2]  += attn * bflo(q0.y); acc[3]  += attn * bfhi(q0.y);
        acc[4]  += attn * bflo(q0.z); acc[5]  += attn * bfhi(q0.z);
        acc[6]  += attn * bflo(q0.w); acc[7]  += attn * bfhi(q0.w);
        acc[8]  += attn * bflo(q1.x); acc[9]  += attn * bfhi(q1.x);
        acc[10] += attn * bflo(q1.y); acc[11] += attn * bfhi(q1.y);
        acc[12] += attn * bflo(q1.z); acc[13] += attn * bfhi(q1.z);
        acc[14] += attn * bflo(q1.w); acc[15] += attn * bfhi(q1.w);
    }
    #pragma unroll
    for (int i = 0; i < 16; ++i) {
        acc[i] += __shfl_xor(acc[i], 8, 64);
        acc[i] += __shfl_xor(acc[i], 16, 64);
        acc[i] += __shfl_xor(acc[i], 32, 64);
    }
    if (es == 0) {
        float4* orow = (float4*)(outp + (size_t)n * MD + h * DV);
        #pragma unroll
        for (int i = 0; i < 4; ++i) {
            float4 o = orow[i];
            o.x += acc[i * 4 + 0]; o.y += acc[i * 4 + 1];
            o.z += acc[i * 4 + 2]; o.w += acc[i * 4 + 3];
            orow[i] = o;
        }
    }
}

// ---------------------------------------------------------------------------
extern "C" void kernel_launch(void* const* d_in, const int* in_sizes, int n_in,
                              void* d_out, int out_size, void* d_ws, size_t ws_size,
                              hipStream_t stream) {
    const float* inp  = (const float*)d_in[0];
    const int*   ei   = (const int*)d_in[1];
    const float* dist = (const float*)d_in[2];
    const float* Wv   = (const float*)d_in[4];
    const float* wsrc = (const float*)d_in[5];
    const float* wtgt = (const float*)d_in[6];
    const float* Ws   = (const float*)d_in[7];
    const float* bias = (const float*)d_in[8];

    float* outp = (float*)d_out;
    float* attn = outp + (size_t)N_NODES * MD;

    float*  wsf     = (float*)d_ws;
    float*  B       = wsf;                                     // 128 KB
    float*  vs      = B + 32768;                               // 1.6 MB
    float*  vt      = vs + N_NODES * NH;                       // 1.6 MB
    ushort* value16 = (ushort*)(vt + N_NODES * NH);            // 12.8 MB
    int2*   csr     = (int2*)(value16 + (size_t)N_NODES * MD); // 12.8 MB
    float*  fdist   = (float*)(csr + N_EDGES);                 // 6.4 MB
    ushort* slot16  = (ushort*)(fdist + N_EDGES);              // 3.2 MB
    int*    deg     = (int*)(slot16 + N_EDGES);                // 50000
    int*    rowptr  = deg + N_NODES;                           // 50001
    int*    bsum    = rowptr + N_NODES + 1;                    // 256
    int*    boff    = bsum + 256;                              // 256

    hipMemsetAsync(deg, 0, (size_t)N_NODES * sizeof(int), stream);

    k0_prep<<<128, 256, 0, stream>>>(Wv, Ws, B);
    k_front<<<GEMM_NBLK + SLOT_NBLK, 256, 0, stream>>>(
        inp, B, bias, wsrc, wtgt, value16, vs, vt, outp, ei, deg, slot16);
    k_scan1<<<SCAN_NBLK, 256, 0, stream>>>(deg, rowptr, bsum);
    k_scan2<<<1, 256, 0, stream>>>(bsum, boff);
    k_scan3<<<SCAN_NBLK, 256, 0, stream>>>(rowptr, boff);
    k_place<<<(N_EDGES / 4 + 255) / 256, 256, 0, stream>>>(ei, rowptr, slot16,
                                                           dist, csr, fdist);
    k_gather<<<(N_NODES + 3) / 4, 256, 0, stream>>>(csr, rowptr, fdist, vs, vt,
                                                    value16, outp, attn);
}